// Round 16
// baseline (46.482 us; speedup 1.0000x reference)
//
#include <hip/hip_runtime.h>

#define N_NODES 50000
#define N_EDGES 800000
#define D_FEAT  96
#define ROW_BYTES 192                 // bf16 row: 96*2 B = 12 granules x 16B
#define LPR 12                        // lanes per row (1 granule each)
#define RPB 32                        // rows per block
#define BLOCK (RPB * LPR)             // 384
#define LDS_EDGES 2048                // block edge segment capacity (avg 512)
#define EB 8                          // edges per batch; 2 batches in flight

#define N_CVT  (N_NODES * D_FEAT / 8) // 600000 convert work-items
#define CONV_BLOCKS ((N_CVT + 255) / 256)         // 2344
#define SEARCH_BLOCKS ((N_NODES + 1 + 255) / 256) // 196
#define EMB_OFF 200192                // after row_ptr (200004 B), 16B-aligned
#define WS_NEEDED (EMB_OFF + (size_t)N_NODES * D_FEAT * 2)

typedef unsigned int u32x4 __attribute__((ext_vector_type(4)));

__device__ __forceinline__ u32x4 gload16(const void* p) {
    u32x4 r;
    asm volatile("global_load_dwordx4 %0, %1, off" : "=v"(r) : "v"(p));
    return r;
}

// wait until <= n vector-memory ops outstanding, then fence the scheduler
// (rule #18: sched_barrier so ALU consumers aren't hoisted above the wait).
#define PIPE_WAIT(n) do {                                              \
    asm volatile("s_waitcnt vmcnt(" #n ")" ::: "memory");              \
    __builtin_amdgcn_sched_barrier(0);                                 \
} while (0)

__device__ __forceinline__ unsigned int f2bf(float f) {  // RNE f32->bf16
    unsigned u = __float_as_uint(f);
    return (u + 0x7fffu + ((u >> 16) & 1u)) >> 16;
}

__device__ __forceinline__ void accum8(u32x4 m, float v, float4& A, float4& B) {
    A.x += v * __uint_as_float(m[0] << 16);
    A.y += v * __uint_as_float(m[0] & 0xffff0000u);
    A.z += v * __uint_as_float(m[1] << 16);
    A.w += v * __uint_as_float(m[1] & 0xffff0000u);
    B.x += v * __uint_as_float(m[2] << 16);
    B.y += v * __uint_as_float(m[2] & 0xffff0000u);
    B.z += v * __uint_as_float(m[3] << 16);
    B.w += v * __uint_as_float(m[3] & 0xffff0000u);
}

// Prep with DISJOINT block roles (pure control-flow change, no new
// intrinsics — round 15's nontemporal builtins perturbed the asm pipeline's
// regalloc and produced NaN): blocks [0, CONV_BLOCKS) convert f32->bf16;
// blocks [CONV_BLOCKS, +SEARCH_BLOCKS) binary-search row_ptr, overlapping
// the search's dependent-load chain with the BW-bound conversion.
__global__ void prep_kernel(const int* __restrict__ rows,
                            const float* __restrict__ embeds,
                            unsigned int* __restrict__ emb_bf,
                            int* __restrict__ row_ptr) {
    const int b = blockIdx.x;
    if (b < CONV_BLOCKS) {
        const int idx = b * 256 + threadIdx.x;
        if (idx < N_CVT) {
            const float4* src = (const float4*)embeds;
            float4 a = src[idx * 2 + 0];
            float4 c = src[idx * 2 + 1];
            uint4 p;
            p.x = f2bf(a.x) | (f2bf(a.y) << 16);
            p.y = f2bf(a.z) | (f2bf(a.w) << 16);
            p.z = f2bf(c.x) | (f2bf(c.y) << 16);
            p.w = f2bf(c.z) | (f2bf(c.w) << 16);
            ((uint4*)emb_bf)[idx] = p;
        }
    } else {
        const int idx = (b - CONV_BLOCKS) * 256 + threadIdx.x;
        if (idx <= N_NODES) {
            int lo = 0, hi = N_EDGES;
            while (lo < hi) {
                int mid = (lo + hi) >> 1;
                if (rows[mid] < idx) lo = mid + 1;
                else hi = mid;
            }
            row_ptr[idx] = lo;
        }
    }
}

// issue one batch of 8 gathers (indices clamped to staged range; slots past
// the row's end load harmless real data that ACCB multiplies by v=0)
#define ISSUE(i, M0, M1, M2, M3, M4, M5, M6, M7) do {                  \
    int bx_ = start + (i) * EB;                                        \
    int j0_ = bx_ + 0; j0_ = j0_ > ncl ? ncl : j0_;                    \
    int j1_ = bx_ + 1; j1_ = j1_ > ncl ? ncl : j1_;                    \
    int j2_ = bx_ + 2; j2_ = j2_ > ncl ? ncl : j2_;                    \
    int j3_ = bx_ + 3; j3_ = j3_ > ncl ? ncl : j3_;                    \
    int j4_ = bx_ + 4; j4_ = j4_ > ncl ? ncl : j4_;                    \
    int j5_ = bx_ + 5; j5_ = j5_ > ncl ? ncl : j5_;                    \
    int j6_ = bx_ + 6; j6_ = j6_ > ncl ? ncl : j6_;                    \
    int j7_ = bx_ + 7; j7_ = j7_ > ncl ? ncl : j7_;                    \
    M0 = gload16(embB + (size_t)s_cols[j0_] * ROW_BYTES);              \
    M1 = gload16(embB + (size_t)s_cols[j1_] * ROW_BYTES);              \
    M2 = gload16(embB + (size_t)s_cols[j2_] * ROW_BYTES);              \
    M3 = gload16(embB + (size_t)s_cols[j3_] * ROW_BYTES);              \
    M4 = gload16(embB + (size_t)s_cols[j4_] * ROW_BYTES);              \
    M5 = gload16(embB + (size_t)s_cols[j5_] * ROW_BYTES);              \
    M6 = gload16(embB + (size_t)s_cols[j6_] * ROW_BYTES);              \
    M7 = gload16(embB + (size_t)s_cols[j7_] * ROW_BYTES);              \
} while (0)

#define ACCB(i, M0, M1, M2, M3, M4, M5, M6, M7) do {                   \
    int bx_ = start + (i) * EB;                                        \
    int s0_ = bx_ + 0; float v0_ = s_vals[s0_ > ncl ? ncl : s0_];      \
    int s1_ = bx_ + 1; float v1_ = s_vals[s1_ > ncl ? ncl : s1_];      \
    int s2_ = bx_ + 2; float v2_ = s_vals[s2_ > ncl ? ncl : s2_];      \
    int s3_ = bx_ + 3; float v3_ = s_vals[s3_ > ncl ? ncl : s3_];      \
    int s4_ = bx_ + 4; float v4_ = s_vals[s4_ > ncl ? ncl : s4_];      \
    int s5_ = bx_ + 5; float v5_ = s_vals[s5_ > ncl ? ncl : s5_];      \
    int s6_ = bx_ + 6; float v6_ = s_vals[s6_ > ncl ? ncl : s6_];      \
    int s7_ = bx_ + 7; float v7_ = s_vals[s7_ > ncl ? ncl : s7_];      \
    v0_ = (s0_ < lend) ? v0_ : 0.f;  v1_ = (s1_ < lend) ? v1_ : 0.f;   \
    v2_ = (s2_ < lend) ? v2_ : 0.f;  v3_ = (s3_ < lend) ? v3_ : 0.f;   \
    v4_ = (s4_ < lend) ? v4_ : 0.f;  v5_ = (s5_ < lend) ? v5_ : 0.f;   \
    v6_ = (s6_ < lend) ? v6_ : 0.f;  v7_ = (s7_ < lend) ? v7_ : 0.f;   \
    accum8(M0, v0_, aA, aB); accum8(M1, v1_, aA, aB);                  \
    accum8(M2, v2_, aA, aB); accum8(M3, v3_, aA, aB);                  \
    accum8(M4, v4_, aA, aB); accum8(M5, v5_, aA, aB);                  \
    accum8(M6, v6_, aA, aB); accum8(M7, v7_, aA, aB);                  \
} while (0)

// SpMM — byte-exact round-11 structure (proven pass, 45.9 us): 32
// consecutive rows/block, cols/vals staged in LDS with PLAIN loads,
// depth-2 same-body asm pipeline (16 tuples; never drain mid-burst),
// plain output stores. No nontemporal intrinsics anywhere near the
// counted-vmcnt pipeline.
__global__ __launch_bounds__(BLOCK, 2) void spmm_kernel(
    const int*          __restrict__ cols,
    const float*        __restrict__ vals,
    const unsigned int* __restrict__ emb_bf,
    const int*          __restrict__ row_ptr,
    float*              __restrict__ out) {
    __shared__ int   s_cols[LDS_EDGES];
    __shared__ float s_vals[LDS_EDGES];

    const int tid  = threadIdx.x;
    const int base = blockIdx.x * RPB;
    const int rlim = (base + RPB < N_NODES) ? base + RPB : N_NODES;
    const int e0   = row_ptr[base];
    const int n_e  = row_ptr[rlim] - e0;
    const bool fits = (n_e <= LDS_EDGES);

    if (fits) {
        for (int j = tid; j < n_e; j += BLOCK) {
            s_cols[j] = cols[e0 + j];
            s_vals[j] = vals[e0 + j];
        }
    }
    __syncthreads();

    const int lrow = tid / LPR;
    const int fg   = tid - lrow * LPR;
    const int r    = base + lrow;
    if (r >= N_NODES) return;

    const int start = row_ptr[r]     - e0;
    const int lend  = row_ptr[r + 1] - e0;
    const char* embB = (const char*)emb_bf + fg * 16;

    float4 aA = make_float4(0.f, 0.f, 0.f, 0.f);
    float4 aB = aA;
    float4* o = (float4*)out;
    const size_t ob = (size_t)r * 24 + fg * 2;

    if (!fits) {   // safety path (not taken for this distribution)
        for (int e = e0 + start; e < e0 + lend; ++e) {
            int   c = cols[e];
            float v = vals[e];
            u32x4 m = *(const u32x4*)(embB + (size_t)c * ROW_BYTES);
            accum8(m, v, aA, aB);
        }
        o[ob + 0] = aA; o[ob + 1] = aB;
        return;
    }

    if (n_e == 0) {
        o[ob + 0] = aA; o[ob + 1] = aB;
        return;
    }
    const int ncl = n_e - 1;
    const int nB  = (lend - start + EB - 1) / EB;   // 8-edge batches

    u32x4 A0, A1, A2, A3, A4, A5, A6, A7;
    u32x4 B0, B1, B2, B3, B4, B5, B6, B7;

    int i = 0;
    for (; i + 1 < nB; i += 2) {
        ISSUE(i,     A0, A1, A2, A3, A4, A5, A6, A7);
        ISSUE(i + 1, B0, B1, B2, B3, B4, B5, B6, B7);
        PIPE_WAIT(8);          // A complete; B's 8 still in flight
        ACCB(i,     A0, A1, A2, A3, A4, A5, A6, A7);
        PIPE_WAIT(0);          // B complete
        ACCB(i + 1, B0, B1, B2, B3, B4, B5, B6, B7);
    }
    if (i < nB) {
        ISSUE(i, A0, A1, A2, A3, A4, A5, A6, A7);
        PIPE_WAIT(0);
        ACCB(i, A0, A1, A2, A3, A4, A5, A6, A7);
    }

    o[ob + 0] = aA;
    o[ob + 1] = aB;
}

// ---------- fallback f32 path (ws too small; proven round-2/5) ----------
#define F4 (D_FEAT / 4)
__global__ __launch_bounds__(384, 2) void spmm_f32_kernel(
    const int*   __restrict__ cols,
    const float* __restrict__ vals,
    const float* __restrict__ embeds,
    const int*   __restrict__ row_ptr,
    float*       __restrict__ out) {
    const int tid       = threadIdx.x;
    const int local_row = tid / F4;
    const int fg        = tid - local_row * F4;
    const int r         = blockIdx.x * 16 + local_row;
    if (r >= N_NODES) return;
    const float4* __restrict__ emb4 = (const float4*)embeds;
    int e = row_ptr[r], end = row_ptr[r + 1];
    float4 a0 = make_float4(0.f, 0.f, 0.f, 0.f), a1 = a0, a2 = a0, a3 = a0;
    for (; e + 3 < end; e += 4) {
        int c0 = cols[e], c1 = cols[e + 1], c2 = cols[e + 2], c3 = cols[e + 3];
        float v0 = vals[e], v1 = vals[e + 1], v2 = vals[e + 2], v3 = vals[e + 3];
        float4 m0 = emb4[c0 * F4 + fg], m1 = emb4[c1 * F4 + fg];
        float4 m2 = emb4[c2 * F4 + fg], m3 = emb4[c3 * F4 + fg];
        a0.x += v0 * m0.x; a0.y += v0 * m0.y; a0.z += v0 * m0.z; a0.w += v0 * m0.w;
        a1.x += v1 * m1.x; a1.y += v1 * m1.y; a1.z += v1 * m1.z; a1.w += v1 * m1.w;
        a2.x += v2 * m2.x; a2.y += v2 * m2.y; a2.z += v2 * m2.z; a2.w += v2 * m2.w;
        a3.x += v3 * m3.x; a3.y += v3 * m3.y; a3.z += v3 * m3.z; a3.w += v3 * m3.w;
    }
    for (; e < end; ++e) {
        int c = cols[e]; float v = vals[e];
        float4 m = emb4[c * F4 + fg];
        a0.x += v * m.x; a0.y += v * m.y; a0.z += v * m.z; a0.w += v * m.w;
    }
    float4 s;
    s.x = (a0.x + a1.x) + (a2.x + a3.x);
    s.y = (a0.y + a1.y) + (a2.y + a3.y);
    s.z = (a0.z + a1.z) + (a2.z + a3.z);
    s.w = (a0.w + a1.w) + (a2.w + a3.w);
    ((float4*)out)[r * F4 + fg] = s;
}

__global__ void build_row_ptr_kernel(const int* __restrict__ rows,
                                     int* __restrict__ row_ptr) {
    int r = blockIdx.x * blockDim.x + threadIdx.x;
    if (r > N_NODES) return;
    int lo = 0, hi = N_EDGES;
    while (lo < hi) {
        int mid = (lo + hi) >> 1;
        if (rows[mid] < r) lo = mid + 1;
        else hi = mid;
    }
    row_ptr[r] = lo;
}

extern "C" void kernel_launch(void* const* d_in, const int* in_sizes, int n_in,
                              void* d_out, int out_size, void* d_ws, size_t ws_size,
                              hipStream_t stream) {
    const int*   rows   = (const int*)  d_in[0];
    const int*   cols   = (const int*)  d_in[1];
    const float* vals   = (const float*)d_in[2];
    const float* embeds = (const float*)d_in[3];
    float*       out    = (float*)      d_out;

    int* row_ptr = (int*)d_ws;

    if (ws_size >= WS_NEEDED) {
        unsigned int* emb_bf = (unsigned int*)((char*)d_ws + EMB_OFF);
        {
            int blocks = CONV_BLOCKS + SEARCH_BLOCKS;        // 2540
            prep_kernel<<<blocks, 256, 0, stream>>>(rows, embeds, emb_bf,
                                                    row_ptr);
        }
        {
            int blocks = (N_NODES + RPB - 1) / RPB;          // 1563
            spmm_kernel<<<blocks, BLOCK, 0, stream>>>(cols, vals, emb_bf,
                                                      row_ptr, out);
        }
    } else {
        {
            int threads = 256;
            int blocks  = (N_NODES + 1 + threads - 1) / threads;
            build_row_ptr_kernel<<<blocks, threads, 0, stream>>>(rows, row_ptr);
        }
        {
            int blocks = (N_NODES + 15) / 16;
            spmm_f32_kernel<<<blocks, 384, 0, stream>>>(cols, vals, embeds,
                                                        row_ptr, out);
        }
    }
}